// Round 6
// baseline (303.169 us; speedup 1.0000x reference)
//
#include <hip/hip_runtime.h>

// VecInt: scaling-and-squaring integration, vel [2,128,128,128,3] fp32.
// v = vel/2^7; 7x: v = v + warp(v, v)  (border-clipped trilinear).
//
// Round-6: round-5 (fp16x4 padded intermediates, 8B loads) + ONE change:
// XCD-aware block swizzle.  Consecutive physical blocks round-robin across
// 8 XCDs; remap so each XCD owns a contiguous ~4.2MB x-slab of the field,
// so the +-1-voxel gather neighborhood lives in the local 4MB L2.
// Round-3 proved the swizzle halves FETCH_SIZE; its regression came from
// the z-pairing it was combined with (VGPR=32 serialized the chains).

#define NVOX_PER_B (1 << 21)          // 128^3

typedef _Float16 h16;
typedef __attribute__((ext_vector_type(4))) _Float16 h16x4;   // 8 bytes

__device__ __forceinline__ int swizzle_idx()
{
    int blk = blockIdx.x;
    int nb  = gridDim.x;
    // bijective when nb % 8 == 0: XCD c (blk%8==c) gets logical range
    // [c*nb/8, (c+1)*nb/8) = one contiguous x-slab.
    int lblk = ((nb & 7) == 0) ? ((blk & 7) * (nb >> 3) + (blk >> 3)) : blk;
    return lblk * (int)blockDim.x + (int)threadIdx.x;
}

// ---- shared address/weight computation --------------------------------
__device__ __forceinline__ void tri_setup(
    int x, int y, int z, float fx, float fy, float fz,
    int* off, float* w)
{
    float lx = fminf(fmaxf((float)x + fx, 0.0f), 127.0f);
    float ly = fminf(fmaxf((float)y + fy, 0.0f), 127.0f);
    float lz = fminf(fmaxf((float)z + fz, 0.0f), 127.0f);

    float flx = floorf(lx), fly = floorf(ly), flz = floorf(lz);
    float wx1 = lx - flx, wy1 = ly - fly, wz1 = lz - flz;
    float wx0 = 1.0f - wx1, wy0 = 1.0f - wy1, wz0 = 1.0f - wz1;

    int x0 = (int)flx, y0 = (int)fly, z0 = (int)flz;
    int x1 = min(x0 + 1, 127);
    int y1 = min(y0 + 1, 127);
    int z1 = min(z0 + 1, 127);

    off[0] = (x0 << 14) + (y0 << 7) + z0;
    off[1] = (x0 << 14) + (y0 << 7) + z1;
    off[2] = (x0 << 14) + (y1 << 7) + z0;
    off[3] = (x0 << 14) + (y1 << 7) + z1;
    off[4] = (x1 << 14) + (y0 << 7) + z0;
    off[5] = (x1 << 14) + (y0 << 7) + z1;
    off[6] = (x1 << 14) + (y1 << 7) + z0;
    off[7] = (x1 << 14) + (y1 << 7) + z1;
    w[0] = wx0 * wy0 * wz0;  w[1] = wx0 * wy0 * wz1;
    w[2] = wx0 * wy1 * wz0;  w[3] = wx0 * wy1 * wz1;
    w[4] = wx1 * wy0 * wz0;  w[5] = wx1 * wy0 * wz1;
    w[6] = wx1 * wy1 * wz0;  w[7] = wx1 * wy1 * wz1;
}

__device__ __forceinline__ void sample_h4(
    const h16x4* __restrict__ vb, const int* off, const float* w,
    float& ox, float& oy, float& oz)
{
    ox = 0.0f; oy = 0.0f; oz = 0.0f;
#pragma unroll
    for (int c = 0; c < 8; ++c) {
        h16x4 cv = vb[off[c]];
        ox += w[c] * (float)cv.x;
        oy += w[c] * (float)cv.y;
        oz += w[c] * (float)cv.z;
    }
}

// ---- step 1: f32 packed vel -> fp16x4 field (fuses the /128 scale) -----
__global__ __launch_bounds__(256) void vecint_first(
    const float* __restrict__ vin, h16x4* __restrict__ vout,
    float scale, int nvox)
{
    int idx = swizzle_idx();
    if (idx >= nvox) return;

    int z = idx & 127;
    int y = (idx >> 7) & 127;
    int x = (idx >> 14) & 127;
    int b = idx >> 21;

    int base = idx * 3;
    float fx = vin[base + 0] * scale;
    float fy = vin[base + 1] * scale;
    float fz = vin[base + 2] * scale;

    int off[8]; float w[8];
    tri_setup(x, y, z, fx, fy, fz, off, w);

    const float* vb = vin + (size_t)b * (NVOX_PER_B * 3);
    float ox = 0.0f, oy = 0.0f, oz = 0.0f;
#pragma unroll
    for (int c = 0; c < 8; ++c) {
        const float* p = vb + (size_t)off[c] * 3;
        ox += w[c] * p[0]; oy += w[c] * p[1]; oz += w[c] * p[2];
    }

    h16x4 o;
    o.x = (h16)(fx + scale * ox);
    o.y = (h16)(fy + scale * oy);
    o.z = (h16)(fz + scale * oz);
    o.w = (h16)0.0f;
    vout[idx] = o;
}

// ---- steps 2..6: fp16x4 -> fp16x4 --------------------------------------
__global__ __launch_bounds__(256) void vecint_mid(
    const h16x4* __restrict__ vin, h16x4* __restrict__ vout, int nvox)
{
    int idx = swizzle_idx();
    if (idx >= nvox) return;

    int z = idx & 127;
    int y = (idx >> 7) & 127;
    int x = (idx >> 14) & 127;
    int b = idx >> 21;

    h16x4 f = vin[idx];
    float fx = (float)f.x, fy = (float)f.y, fz = (float)f.z;

    int off[8]; float w[8];
    tri_setup(x, y, z, fx, fy, fz, off, w);

    const h16x4* vb = vin + ((size_t)b << 21);
    float ox, oy, oz;
    sample_h4(vb, off, w, ox, oy, oz);

    h16x4 o;
    o.x = (h16)(fx + ox);
    o.y = (h16)(fy + oy);
    o.z = (h16)(fz + oz);
    o.w = (h16)0.0f;
    vout[idx] = o;
}

// ---- step 7: fp16x4 -> f32 packed --------------------------------------
__global__ __launch_bounds__(256) void vecint_last(
    const h16x4* __restrict__ vin, float* __restrict__ vout, int nvox)
{
    int idx = swizzle_idx();
    if (idx >= nvox) return;

    int z = idx & 127;
    int y = (idx >> 7) & 127;
    int x = (idx >> 14) & 127;
    int b = idx >> 21;

    h16x4 f = vin[idx];
    float fx = (float)f.x, fy = (float)f.y, fz = (float)f.z;

    int off[8]; float w[8];
    tri_setup(x, y, z, fx, fy, fz, off, w);

    const h16x4* vb = vin + ((size_t)b << 21);
    float ox, oy, oz;
    sample_h4(vb, off, w, ox, oy, oz);

    int base = idx * 3;
    vout[base + 0] = fx + ox;
    vout[base + 1] = fy + oy;
    vout[base + 2] = fz + oz;
}

extern "C" void kernel_launch(void* const* d_in, const int* in_sizes, int n_in,
                              void* d_out, int out_size, void* d_ws, size_t ws_size,
                              hipStream_t stream) {
    const float* vel = (const float*)d_in[0];
    float* out = (float*)d_out;

    int nvox = in_sizes[0] / 3;            // 4,194,304 voxels (2 batches)
    int blocks = (nvox + 255) / 256;       // 16384
    float s0 = 1.0f / 128.0f;              // 1 / 2^INT_STEPS

    // D = fp16 field in the first 33.5 MB of d_out; W = fp16 field in d_ws.
    h16x4* D = (h16x4*)d_out;
    h16x4* W = (h16x4*)d_ws;

    vecint_first<<<blocks, 256, 0, stream>>>(vel, D, s0, nvox);   // 1: vel->D
    vecint_mid  <<<blocks, 256, 0, stream>>>(D, W, nvox);         // 2: D->W
    vecint_mid  <<<blocks, 256, 0, stream>>>(W, D, nvox);         // 3: W->D
    vecint_mid  <<<blocks, 256, 0, stream>>>(D, W, nvox);         // 4: D->W
    vecint_mid  <<<blocks, 256, 0, stream>>>(W, D, nvox);         // 5: W->D
    vecint_mid  <<<blocks, 256, 0, stream>>>(D, W, nvox);         // 6: D->W
    vecint_last <<<blocks, 256, 0, stream>>>(W, out, nvox);       // 7: W->out (f32)
}